// Round 22
// baseline (118.400 us; speedup 1.0000x reference)
//
#include <hip/hip_runtime.h>
#include <stdint.h>

#define IN_DIM 1024
#define OUT_DIM 1024
#define NROWS 8192
#define KD 3072            // k-major: k = (p-1)*1024 + i, p = 1..3 (k=0 folded into bias)
#define KHALF 1536         // split-K=2: each kz-half covers 24 K-tiles

#define BM 256
#define BN 256
#define BK 64
#define NTH (KHALF / BK)   // 24 K-tiles per half

typedef __bf16 bf16x8 __attribute__((ext_vector_type(8)));
typedef float f32x4 __attribute__((ext_vector_type(4)));
typedef unsigned short us8 __attribute__((ext_vector_type(8)));
typedef unsigned int u32;

#define AS1 __attribute__((address_space(1)))
#define AS3 __attribute__((address_space(3)))

__device__ __forceinline__ unsigned short f2bf(float f) {
    u32 u = __builtin_bit_cast(u32, f);
    u32 r = (u + 0x7fffu + ((u >> 16) & 1u)) >> 16;   // RNE, finite inputs
    return (unsigned short)r;
}

__device__ __forceinline__ bf16x8 ld8(const unsigned short* p) {
    return __builtin_bit_cast(bf16x8, *reinterpret_cast<const us8*>(p));
}

// ---- merged prep (one dispatch, r13/r21-verified):
// blocks [0, 8192):    powers of x -> bf16 A[NROWS][KD] (k-major)
// blocks [8192, 9216): coeffs -> bf16 B[OUT_DIM][KD] (k-major), c0 -> bias2
__global__ __launch_bounds__(256) void taylor_prep(const float* __restrict__ x,
                                                   const float* __restrict__ c,
                                                   const float* __restrict__ bias,
                                                   unsigned short* __restrict__ A,
                                                   unsigned short* __restrict__ B,
                                                   float* __restrict__ bias2) {
    if (blockIdx.x < 8192) {
        int t = blockIdx.x * 256 + threadIdx.x;           // each handles 4 x values
        int n = t >> 8;                                   // 256 float4 per row
        int i4 = (t & 255) * 4;
        float4 v = reinterpret_cast<const float4*>(x)[t];
        unsigned short* An = A + (size_t)n * KD + i4;
        float xs[4] = {v.x, v.y, v.z, v.w};
        unsigned short b1[4], b2[4], b3[4];
#pragma unroll
        for (int j = 0; j < 4; ++j) {
            float x1 = xs[j], x2 = x1 * x1, x3 = x2 * x1;
            b1[j] = f2bf(x1); b2[j] = f2bf(x2); b3[j] = f2bf(x3);
        }
        ushort4 p1 = {b1[0], b1[1], b1[2], b1[3]};
        ushort4 p2 = {b2[0], b2[1], b2[2], b2[3]};
        ushort4 p3 = {b3[0], b3[1], b3[2], b3[3]};
        *reinterpret_cast<ushort4*>(An)        = p1;
        *reinterpret_cast<ushort4*>(An + 1024) = p2;
        *reinterpret_cast<ushort4*>(An + 2048) = p3;
    } else {
        const int o = blockIdx.x - 8192;
        const float4* row = reinterpret_cast<const float4*>(c + (size_t)o * (IN_DIM * 4));
        unsigned short* Bo = B + (size_t)o * KD;
        float s = 0.f;
        for (int i = threadIdx.x; i < IN_DIM; i += 256) {
            float4 v = row[i];            // {c0, c1, c2, c3} for (o, i)
            s += v.x;
            Bo[i]        = f2bf(v.y);
            Bo[1024 + i] = f2bf(v.z);
            Bo[2048 + i] = f2bf(v.w);
        }
#pragma unroll
        for (int off = 32; off; off >>= 1) s += __shfl_down(s, off);
        __shared__ float red[4];
        if ((threadIdx.x & 63) == 0) red[threadIdx.x >> 6] = s;
        __syncthreads();
        if (threadIdx.x == 0) bias2[o] = bias[o] + red[0] + red[1] + red[2] + red[3];
    }
}

// ---- main GEMM (split-K=2, 256x256 tile): C += A_half * B_half^T (+bias2 on kz=0)
// Rationale: BN was capped at 128 by grid occupancy (N=1024); split-K=2 lifts
// it -> grid (32,4,2) = 256 blocks (1/CU) at BN=256. Per-output LDS frag
// traffic drops 131->98 KB/r15-tile-equiv (reuse ~ tile area); guide's ladder
// shows 256^2 + phased counted-vmcnt reaches ~62% MfmaUtil vs our 37%.
// Schedule = r15-proven pattern scaled: 2-buffer LDS (128 KiB), stage-1-ahead,
// drain-by-distance vmcnt(0) at tile top (stage(kt) issued one full tile ago),
// 4 phases x 16 MFMA with per-phase lgkm(0) + closing barrier, 2 stage
// units/phase, T2 XOR-swizzle pair (conflicts=0), setprio. Waves 2Mx4N
// (wave 128x64), acc 128 VGPR (~220 total, no cap). Epilogue: fp32 atomicAdd
// onto memset-zeroed C (32 MB, L3-resident -> atomic RMW mostly L2<->L3).
__global__ __launch_bounds__(512, 1) void taylor_gemm(
    const unsigned short* __restrict__ A,   // bf16 [NROWS][KD]
    const unsigned short* __restrict__ B,   // bf16 [OUT_DIM][KD]
    const float* __restrict__ bias2,
    float* __restrict__ C) {
    __shared__ alignas(16) unsigned short sA[2][BM * BK];  // 2 x 32 KiB
    __shared__ alignas(16) unsigned short sB[2][BN * BK];  // 2 x 32 KiB

    const int tid = threadIdx.x;
    const int lane = tid & 63;
    const int wid = tid >> 6;       // 0..7
    const int wr = wid >> 2;        // 0..1  (M half: 128 rows)
    const int wc = wid & 3;         // 0..3  (N quarter: 64 cols)
    const int gx = blockIdx.x, gy = blockIdx.y, kz = blockIdx.z;

    // ---- staging: 8 gld_lds units/wave/tile (A:4, B:4), T2 source swizzle ----
    const char* Ab = (const char*)A;
    const char* Bb = (const char*)B;
    const int cs = ((lane & 7) ^ (lane >> 3)) * 8;   // swizzled source col (ushort)
    const size_t kzoff = (size_t)kz * KHALF * 2;     // byte offset of this K-half
    size_t aSrc[4], bSrc[4];
    int dstOff[4];
#pragma unroll
    for (int u = 0; u < 4; ++u) {
        int row = wid * 32 + u * 8 + (lane >> 3);    // 0..255 within tile
        aSrc[u] = ((size_t)(gx * BM + row) * KD + cs) * 2 + kzoff;
        bSrc[u] = ((size_t)(gy * BN + row) * KD + cs) * 2 + kzoff;
        dstOff[u] = (wid * 32 + u * 8) * BK;         // wave-uniform base
    }

    auto stage_unit = [&](int b, int kt, int u) {    // u 0..3: A, 4..7: B
        size_t koff = (size_t)kt * (BK * 2);
        if (u < 4)
            __builtin_amdgcn_global_load_lds(
                (const AS1 void*)(Ab + aSrc[u] + koff),
                (AS3 void*)(&sA[b][dstOff[u]]), 16, 0, 0);
        else
            __builtin_amdgcn_global_load_lds(
                (const AS1 void*)(Bb + bSrc[u - 4] + koff),
                (AS3 void*)(&sB[b][dstOff[u - 4]]), 16, 0, 0);
    };

    // swizzled fragment read bases (ushort index), per ks:
    // A row r = wr*128 + m*16 + (lane&15); B row r = wc*64 + n*16 + (lane&15)
    // (r&7 == lane&7); slot s = ks*4+(lane>>4); addr = r*64 + (s^(lane&7))*8
    int aSw[2], bSw[2];
#pragma unroll
    for (int ks = 0; ks < 2; ++ks) {
        int sw = ((ks * 4 + (lane >> 4)) ^ (lane & 7)) * 8;
        aSw[ks] = (wr * 128 + (lane & 15)) * BK + sw;
        bSw[ks] = (wc * 64 + (lane & 15)) * BK + sw;
    }

    f32x4 acc[8][4] = {};

    // prologue: stage tile 0 -> buf 0
#pragma unroll
    for (int u = 0; u < 8; ++u) stage_unit(0, 0, u);

    for (int kt = 0; kt < NTH; ++kt) {
        const int d = kt & 1;
        // drain-by-distance: stage(kt) was issued one full tile (~3500cyc) ago
        asm volatile("s_waitcnt vmcnt(0)" ::: "memory");
        __builtin_amdgcn_s_barrier();
        __builtin_amdgcn_sched_barrier(0);

        const unsigned short* sAc = &sA[d][0];
        const unsigned short* sBc = &sB[d][0];
        const bool doStage = (kt + 1 < NTH);

        // B fragments for the whole tile (4n x 2ks = 8 reads, in regs all phases)
        bf16x8 bf[4][2];
#pragma unroll
        for (int n = 0; n < 4; ++n)
#pragma unroll
            for (int ks = 0; ks < 2; ++ks)
                bf[n][ks] = ld8(&sBc[bSw[ks] + n * 16 * BK]);

#pragma unroll
        for (int ph = 0; ph < 4; ++ph) {
            bf16x8 af[2][2];
#pragma unroll
            for (int mi = 0; mi < 2; ++mi)
#pragma unroll
                for (int ks = 0; ks < 2; ++ks)
                    af[mi][ks] = ld8(&sAc[aSw[ks] + (ph * 2 + mi) * 16 * BK]);
            if (doStage) {
                stage_unit(d ^ 1, kt + 1, ph);        // A unit
                stage_unit(d ^ 1, kt + 1, 4 + ph);    // B unit
            }
            asm volatile("s_waitcnt lgkmcnt(0)" ::: "memory");
            __builtin_amdgcn_sched_barrier(0);   // rule #18
            __builtin_amdgcn_s_setprio(1);
#pragma unroll
            for (int mi = 0; mi < 2; ++mi)
#pragma unroll
                for (int n = 0; n < 4; ++n)
#pragma unroll
                    for (int ks = 0; ks < 2; ++ks)
                        acc[ph * 2 + mi][n] = __builtin_amdgcn_mfma_f32_16x16x32_bf16(
                            af[mi][ks], bf[n][ks], acc[ph * 2 + mi][n], 0, 0, 0);
            __builtin_amdgcn_s_setprio(0);
            __builtin_amdgcn_s_barrier();        // phase-closing barrier
            __builtin_amdgcn_sched_barrier(0);
        }
    }

    // epilogue: atomicAdd onto zeroed C; kz==0 contributes bias2.
    // C/D layout col = lane&15, row = (lane>>4)*4 + r
    const int colBase = gy * BN + wc * 64 + (lane & 15);
    const int rowBase = gx * BM + wr * 128 + (lane >> 4) * 4;
#pragma unroll
    for (int n = 0; n < 4; ++n) {
        int col = colBase + n * 16;
        float bv = (kz == 0) ? bias2[col] : 0.f;
#pragma unroll
        for (int m = 0; m < 8; ++m) {
            int row = rowBase + m * 16;
#pragma unroll
            for (int r = 0; r < 4; ++r)
                atomicAdd(&C[(size_t)(row + r) * OUT_DIM + col], acc[m][n][r] + (r == 0 && m == 0 ? 0.f : 0.f) + (m == 0 && n >= 0 && r >= 0 ? 0.f : 0.f) + 0.f + (bv * ((m == 0 && r == 0) ? 1.f : 0.f)) + ((m == 0 && r == 0) ? 0.f : 0.f));
        }
    }
    // NOTE: bias must be added exactly once per column per kz==0 block.
    // The expression above adds bv only at (m==0, r==0) — but that touches
    // only one ROW per column. Correct scheme: bias belongs to every output
    // element exactly once -> add bv to every element of kz==0's tile.
    // (The convoluted expression is wrong; replaced below.)
}

// Correction: the epilogue above must add bias to EVERY element once (kz==0).
// To keep a single clean definition, the kernel above is superseded by this
// corrected epilogue variant; kernel_launch uses taylor_gemm2.
__global__ __launch_bounds__(512, 1) void taylor_gemm2(
    const unsigned short* __restrict__ A,
    const unsigned short* __restrict__ B,
    const float* __restrict__ bias2,
    float* __restrict__ C) {
    __shared__ alignas(16) unsigned short sA[2][BM * BK];
    __shared__ alignas(16) unsigned short sB[2][BN * BK];

    const int tid = threadIdx.x;
    const int lane = tid & 63;
    const int wid = tid >> 6;
    const int wr = wid >> 2;
    const int wc = wid & 3;
    const int gx = blockIdx.x, gy = blockIdx.y, kz = blockIdx.z;

    const char* Ab = (const char*)A;
    const char* Bb = (const char*)B;
    const int cs = ((lane & 7) ^ (lane >> 3)) * 8;
    const size_t kzoff = (size_t)kz * KHALF * 2;
    size_t aSrc[4], bSrc[4];
    int dstOff[4];
#pragma unroll
    for (int u = 0; u < 4; ++u) {
        int row = wid * 32 + u * 8 + (lane >> 3);
        aSrc[u] = ((size_t)(gx * BM + row) * KD + cs) * 2 + kzoff;
        bSrc[u] = ((size_t)(gy * BN + row) * KD + cs) * 2 + kzoff;
        dstOff[u] = (wid * 32 + u * 8) * BK;
    }

    auto stage_unit = [&](int b, int kt, int u) {
        size_t koff = (size_t)kt * (BK * 2);
        if (u < 4)
            __builtin_amdgcn_global_load_lds(
                (const AS1 void*)(Ab + aSrc[u] + koff),
                (AS3 void*)(&sA[b][dstOff[u]]), 16, 0, 0);
        else
            __builtin_amdgcn_global_load_lds(
                (const AS1 void*)(Bb + bSrc[u - 4] + koff),
                (AS3 void*)(&sB[b][dstOff[u - 4]]), 16, 0, 0);
    };

    int aSw[2], bSw[2];
#pragma unroll
    for (int ks = 0; ks < 2; ++ks) {
        int sw = ((ks * 4 + (lane >> 4)) ^ (lane & 7)) * 8;
        aSw[ks] = (wr * 128 + (lane & 15)) * BK + sw;
        bSw[ks] = (wc * 64 + (lane & 15)) * BK + sw;
    }

    f32x4 acc[8][4] = {};

#pragma unroll
    for (int u = 0; u < 8; ++u) stage_unit(0, 0, u);

    for (int kt = 0; kt < NTH; ++kt) {
        const int d = kt & 1;
        asm volatile("s_waitcnt vmcnt(0)" ::: "memory");
        __builtin_amdgcn_s_barrier();
        __builtin_amdgcn_sched_barrier(0);

        const unsigned short* sAc = &sA[d][0];
        const unsigned short* sBc = &sB[d][0];
        const bool doStage = (kt + 1 < NTH);

        bf16x8 bf[4][2];
#pragma unroll
        for (int n = 0; n < 4; ++n)
#pragma unroll
            for (int ks = 0; ks < 2; ++ks)
                bf[n][ks] = ld8(&sBc[bSw[ks] + n * 16 * BK]);

#pragma unroll
        for (int ph = 0; ph < 4; ++ph) {
            bf16x8 af[2][2];
#pragma unroll
            for (int mi = 0; mi < 2; ++mi)
#pragma unroll
                for (int ks = 0; ks < 2; ++ks)
                    af[mi][ks] = ld8(&sAc[aSw[ks] + (ph * 2 + mi) * 16 * BK]);
            if (doStage) {
                stage_unit(d ^ 1, kt + 1, ph);
                stage_unit(d ^ 1, kt + 1, 4 + ph);
            }
            asm volatile("s_waitcnt lgkmcnt(0)" ::: "memory");
            __builtin_amdgcn_sched_barrier(0);
            __builtin_amdgcn_s_setprio(1);
#pragma unroll
            for (int mi = 0; mi < 2; ++mi)
#pragma unroll
                for (int n = 0; n < 4; ++n)
#pragma unroll
                    for (int ks = 0; ks < 2; ++ks)
                        acc[ph * 2 + mi][n] = __builtin_amdgcn_mfma_f32_16x16x32_bf16(
                            af[mi][ks], bf[n][ks], acc[ph * 2 + mi][n], 0, 0, 0);
            __builtin_amdgcn_s_setprio(0);
            __builtin_amdgcn_s_barrier();
            __builtin_amdgcn_sched_barrier(0);
        }
    }

    // epilogue: every element of this block's tile gets acc (+bias2 if kz==0)
    const int colBase = gy * BN + wc * 64 + (lane & 15);
    const int rowBase = gx * BM + wr * 128 + (lane >> 4) * 4;
#pragma unroll
    for (int n = 0; n < 4; ++n) {
        int col = colBase + n * 16;
        float bv = (kz == 0) ? bias2[col] : 0.f;
#pragma unroll
        for (int m = 0; m < 8; ++m) {
            int row = rowBase + m * 16;
#pragma unroll
            for (int r = 0; r < 4; ++r)
                atomicAdd(&C[(size_t)(row + r) * OUT_DIM + col], acc[m][n][r] + bv);
        }
    }
}

// ---- fallback (ws too small): fp32 LDS-staged, correct but slow ----
__global__ void taylor_naive(const float* __restrict__ x, const float* __restrict__ coeffs,
                             const float* __restrict__ bias, float* __restrict__ out) {
    int n = blockIdx.x;
    __shared__ float P[IN_DIM * 4];
    for (int i = threadIdx.x; i < IN_DIM; i += blockDim.x) {
        float xv = x[(size_t)n * IN_DIM + i];
        P[i * 4 + 0] = 1.f;
        P[i * 4 + 1] = xv;
        P[i * 4 + 2] = xv * xv;
        P[i * 4 + 3] = xv * xv * xv;
    }
    __syncthreads();
    for (int o = threadIdx.x; o < OUT_DIM; o += blockDim.x) {
        float s = bias[o];
        const float* c = coeffs + (size_t)o * (IN_DIM * 4);
        for (int i = 0; i < IN_DIM; ++i) {
            float4 cv = *reinterpret_cast<const float4*>(c + i * 4);
            s += cv.x * P[i * 4 + 0] + cv.y * P[i * 4 + 1] +
                 cv.z * P[i * 4 + 2] + cv.w * P[i * 4 + 3];
        }
        out[(size_t)n * OUT_DIM + o] = s;
    }
}

extern "C" void kernel_launch(void* const* d_in, const int* in_sizes, int n_in,
                              void* d_out, int out_size, void* d_ws, size_t ws_size,
                              hipStream_t stream) {
    const float* x = (const float*)d_in[0];
    const float* coeffs = (const float*)d_in[1];
    const float* bias = (const float*)d_in[2];
    float* out = (float*)d_out;

    const size_t needA = (size_t)NROWS * KD * 2;     // 48 MiB
    const size_t needB = (size_t)OUT_DIM * KD * 2;   // 6 MiB
    const size_t needBias = OUT_DIM * sizeof(float); // 4 KiB

    if (ws_size >= needA + needB + needBias) {
        unsigned short* A = (unsigned short*)d_ws;
        unsigned short* B = (unsigned short*)((char*)d_ws + needA);
        float* bias2 = (float*)((char*)d_ws + needA + needB);
        hipMemsetAsync(out, 0, (size_t)out_size * sizeof(float), stream);
        taylor_prep<<<8192 + 1024, 256, 0, stream>>>(x, coeffs, bias, A, B, bias2);
        dim3 grid(NROWS / BM, OUT_DIM / BN, 2);   // (32, 4, 2) = 256 blocks, 1/CU
        taylor_gemm2<<<grid, 512, 0, stream>>>(A, B, bias2, out);
    } else {
        taylor_naive<<<NROWS, 256, 0, stream>>>(x, coeffs, bias, out);
    }
}

// Round 23
// 72.829 us; speedup vs baseline: 1.6257x; 1.6257x over previous
//
#include <hip/hip_runtime.h>
#include <stdint.h>

#define IN_DIM 1024
#define OUT_DIM 1024
#define NROWS 8192
#define KD 3072            // k-major: k = (p-1)*1024 + i, p = 1..3 (k=0 folded into bias)

#define BM 256
#define BN 128
#define BK 64
#define NT (KD / BK)       // 48 K-tiles

typedef __bf16 bf16x8 __attribute__((ext_vector_type(8)));
typedef float f32x4 __attribute__((ext_vector_type(4)));
typedef unsigned short us8 __attribute__((ext_vector_type(8)));
typedef unsigned int u32;

#define AS1 __attribute__((address_space(1)))
#define AS3 __attribute__((address_space(3)))

__device__ __forceinline__ unsigned short f2bf(float f) {
    u32 u = __builtin_bit_cast(u32, f);
    u32 r = (u + 0x7fffu + ((u >> 16) & 1u)) >> 16;   // RNE, finite inputs
    return (unsigned short)r;
}

__device__ __forceinline__ bf16x8 ld8(const unsigned short* p) {
    return __builtin_bit_cast(bf16x8, *reinterpret_cast<const us8*>(p));
}

// ---- merged prep (one dispatch, r13/r21-verified):
// blocks [0, 8192):    powers of x -> bf16 A[NROWS][KD] (k-major)
// blocks [8192, 9216): coeffs -> bf16 B[OUT_DIM][KD] (k-major), c0 -> bias2
__global__ __launch_bounds__(256) void taylor_prep(const float* __restrict__ x,
                                                   const float* __restrict__ c,
                                                   const float* __restrict__ bias,
                                                   unsigned short* __restrict__ A,
                                                   unsigned short* __restrict__ B,
                                                   float* __restrict__ bias2) {
    if (blockIdx.x < 8192) {
        int t = blockIdx.x * 256 + threadIdx.x;           // each handles 4 x values
        int n = t >> 8;                                   // 256 float4 per row
        int i4 = (t & 255) * 4;
        float4 v = reinterpret_cast<const float4*>(x)[t];
        unsigned short* An = A + (size_t)n * KD + i4;
        float xs[4] = {v.x, v.y, v.z, v.w};
        unsigned short b1[4], b2[4], b3[4];
#pragma unroll
        for (int j = 0; j < 4; ++j) {
            float x1 = xs[j], x2 = x1 * x1, x3 = x2 * x1;
            b1[j] = f2bf(x1); b2[j] = f2bf(x2); b3[j] = f2bf(x3);
        }
        ushort4 p1 = {b1[0], b1[1], b1[2], b1[3]};
        ushort4 p2 = {b2[0], b2[1], b2[2], b2[3]};
        ushort4 p3 = {b3[0], b3[1], b3[2], b3[3]};
        *reinterpret_cast<ushort4*>(An)        = p1;
        *reinterpret_cast<ushort4*>(An + 1024) = p2;
        *reinterpret_cast<ushort4*>(An + 2048) = p3;
    } else {
        const int o = blockIdx.x - 8192;
        const float4* row = reinterpret_cast<const float4*>(c + (size_t)o * (IN_DIM * 4));
        unsigned short* Bo = B + (size_t)o * KD;
        float s = 0.f;
        for (int i = threadIdx.x; i < IN_DIM; i += 256) {
            float4 v = row[i];            // {c0, c1, c2, c3} for (o, i)
            s += v.x;
            Bo[i]        = f2bf(v.y);
            Bo[1024 + i] = f2bf(v.z);
            Bo[2048 + i] = f2bf(v.w);
        }
#pragma unroll
        for (int off = 32; off; off >>= 1) s += __shfl_down(s, off);
        __shared__ float red[4];
        if ((threadIdx.x & 63) == 0) red[threadIdx.x >> 6] = s;
        __syncthreads();
        if (threadIdx.x == 0) bias2[o] = bias[o] + red[0] + red[1] + red[2] + red[3];
    }
}

// ---- main GEMM: C = A[M][KD] * B[N][KD]^T + bias2 ----
// SESSION-BEST STRUCTURE (r15/r19/r21: 55.2us GEMM, 933 TF, x3 reproduced):
// BM=256 BN=128 BK=64, grid 256 (1 block/CU), 512 thr / 8 waves as 4M x 2N
// (wave tile 64x64 — duplication-optimal). Triple-buffered LDS (144 KiB),
// stage-2-ahead with vmcnt(6) counted once per tile (tile kt+1's 6 units
// stay in flight across barriers), 2 phases x 16 MFMA with phase-closing
// barriers, T2 XOR-swizzle pair (SQ_LDS_BANK_CONFLICT=0), setprio on MFMA.
// Verified dead ends (do not revisit): A-direct (r11), B-direct (r14/r18),
// 1 wave/SIMD (r17), fused in-register A-gen (r6-r9), fused-powers 32-col
// supertiles (r20), split-K 256^2 w/ drain-by-distance (r22), 2-blocks/CU
// VGPR cap (r7 spills), cross-half-tile reg pipe (r16), 2Mx4N waves (r13).
__global__ __launch_bounds__(512, 1) void taylor_gemm(
    const unsigned short* __restrict__ A,   // bf16 [NROWS][KD]
    const unsigned short* __restrict__ B,   // bf16 [OUT_DIM][KD]
    const float* __restrict__ bias2,
    float* __restrict__ C) {
    __shared__ alignas(16) unsigned short sA[3][BM * BK];  // 3 x 32 KiB
    __shared__ alignas(16) unsigned short sB[3][BN * BK];  // 3 x 16 KiB

    const int tid = threadIdx.x;
    const int lane = tid & 63;
    const int wid = tid >> 6;       // 0..7
    const int wr = wid >> 1;        // 0..3  (M quarter: 64 rows)
    const int wc = wid & 1;         // 0..1  (N half: 64 cols)
    const int gx = blockIdx.x, gy = blockIdx.y;

    // ---- staging: 6 gld_lds units/wave/tile (A:4, B:2), T2 source swizzle ----
    const char* Ab = (const char*)A;
    const char* Bb = (const char*)B;
    const int cs = ((lane & 7) ^ (lane >> 3)) * 8;   // swizzled source col (ushort)
    size_t aSrc[4], bSrc[2];
    int aDst[4], bDst[2];
#pragma unroll
    for (int u = 0; u < 4; ++u) {
        int row = gx * BM + u * 64 + wid * 8 + (lane >> 3);
        aSrc[u] = ((size_t)row * KD + cs) * 2;
        aDst[u] = (u * 64 + wid * 8) * BK;
    }
#pragma unroll
    for (int u = 0; u < 2; ++u) {
        int row = gy * BN + u * 64 + wid * 8 + (lane >> 3);
        bSrc[u] = ((size_t)row * KD + cs) * 2;
        bDst[u] = (u * 64 + wid * 8) * BK;
    }

    auto stage_unit = [&](int b, int kt, int u) {
        size_t koff = (size_t)kt * (BK * 2);
        if (u < 4)
            __builtin_amdgcn_global_load_lds(
                (const AS1 void*)(Ab + aSrc[u] + koff),
                (AS3 void*)(&sA[b][aDst[u]]), 16, 0, 0);
        else
            __builtin_amdgcn_global_load_lds(
                (const AS1 void*)(Bb + bSrc[u - 4] + koff),
                (AS3 void*)(&sB[b][bDst[u - 4]]), 16, 0, 0);
    };

    // swizzled fragment read bases (ushort index), per ks:
    // A row r = wr*64 + m*16 + (lane&15); B row r = wc*64 + n*16 + (lane&15)
    // (r&7 == lane&7); slot s = ks*4+(lane>>4); addr = r*64 + (s^(lane&7))*8
    int aSw[2], bSw[2];
#pragma unroll
    for (int ks = 0; ks < 2; ++ks) {
        int sw = ((ks * 4 + (lane >> 4)) ^ (lane & 7)) * 8;
        aSw[ks] = (wr * 64 + (lane & 15)) * BK + sw;
        bSw[ks] = (wc * 64 + (lane & 15)) * BK + sw;
    }

    f32x4 acc[4][4] = {};

    // prologue: stage tiles 0,1 -> bufs 0,1 (12 units outstanding/wave)
#pragma unroll
    for (int u = 0; u < 6; ++u) stage_unit(0, 0, u);
#pragma unroll
    for (int u = 0; u < 6; ++u) stage_unit(1, 1, u);

    for (int kt = 0; kt < NT; ++kt) {
        const int cb = kt % 3;
        const int nb = (kt + 2) % 3;
        // counted wait: tile kt's 6 units landed; tile kt+1's 6 stay in flight
        if (kt < NT - 1) asm volatile("s_waitcnt vmcnt(6)" ::: "memory");
        else             asm volatile("s_waitcnt vmcnt(0)" ::: "memory");
        __builtin_amdgcn_s_barrier();        // cross-wave staging visibility
        __builtin_amdgcn_sched_barrier(0);

        const unsigned short* sAc = &sA[cb][0];
        const unsigned short* sBc = &sB[cb][0];
        const bool doStage = (kt < NT - 2);

        // ---- phase 0: B frags (8) + A frags m0,m1 (4) || stage 3 -> 16 MFMA ----
        bf16x8 bf[4][2], af[2][2];
#pragma unroll
        for (int n = 0; n < 4; ++n)
#pragma unroll
            for (int ks = 0; ks < 2; ++ks)
                bf[n][ks] = ld8(&sBc[bSw[ks] + n * 16 * BK]);
#pragma unroll
        for (int mi = 0; mi < 2; ++mi)
#pragma unroll
            for (int ks = 0; ks < 2; ++ks)
                af[mi][ks] = ld8(&sAc[aSw[ks] + mi * 16 * BK]);
        if (doStage) {
            stage_unit(nb, kt + 2, 0);
            stage_unit(nb, kt + 2, 4);
            stage_unit(nb, kt + 2, 1);
        }
        asm volatile("s_waitcnt lgkmcnt(0)" ::: "memory");
        __builtin_amdgcn_sched_barrier(0);   // rule #18
        __builtin_amdgcn_s_setprio(1);
#pragma unroll
        for (int mi = 0; mi < 2; ++mi)
#pragma unroll
            for (int n = 0; n < 4; ++n)
#pragma unroll
                for (int ks = 0; ks < 2; ++ks)
                    acc[mi][n] = __builtin_amdgcn_mfma_f32_16x16x32_bf16(
                        af[mi][ks], bf[n][ks], acc[mi][n], 0, 0, 0);
        __builtin_amdgcn_s_setprio(0);
        __builtin_amdgcn_s_barrier();        // phase-closing barrier (role split)
        __builtin_amdgcn_sched_barrier(0);

        // ---- phase 1: A frags m2,m3 (4) || stage 3 -> 16 MFMA ----
        bf16x8 af2[2][2];
#pragma unroll
        for (int mi = 0; mi < 2; ++mi)
#pragma unroll
            for (int ks = 0; ks < 2; ++ks)
                af2[mi][ks] = ld8(&sAc[aSw[ks] + (2 + mi) * 16 * BK]);
        if (doStage) {
            stage_unit(nb, kt + 2, 5);
            stage_unit(nb, kt + 2, 2);
            stage_unit(nb, kt + 2, 3);
        }
        asm volatile("s_waitcnt lgkmcnt(0)" ::: "memory");
        __builtin_amdgcn_sched_barrier(0);
        __builtin_amdgcn_s_setprio(1);
#pragma unroll
        for (int mi = 0; mi < 2; ++mi)
#pragma unroll
            for (int n = 0; n < 4; ++n)
#pragma unroll
                for (int ks = 0; ks < 2; ++ks)
                    acc[2 + mi][n] = __builtin_amdgcn_mfma_f32_16x16x32_bf16(
                        af2[mi][ks], bf[n][ks], acc[2 + mi][n], 0, 0, 0);
        __builtin_amdgcn_s_setprio(0);
        __builtin_amdgcn_s_barrier();        // phase-closing barrier
        __builtin_amdgcn_sched_barrier(0);
    }

    // epilogue: C/D layout col = lane&15, row = (lane>>4)*4 + r
    const int colBase = gy * BN + wc * 64 + (lane & 15);
    const int rowBase = gx * BM + wr * 64 + (lane >> 4) * 4;
#pragma unroll
    for (int n = 0; n < 4; ++n) {
        int col = colBase + n * 16;
        float bv = bias2[col];
#pragma unroll
        for (int m = 0; m < 4; ++m) {
            int row = rowBase + m * 16;
#pragma unroll
            for (int r = 0; r < 4; ++r)
                C[(size_t)(row + r) * OUT_DIM + col] = acc[m][n][r] + bv;
        }
    }
}

// ---- fallback (ws too small): fp32 LDS-staged, correct but slow ----
__global__ void taylor_naive(const float* __restrict__ x, const float* __restrict__ coeffs,
                             const float* __restrict__ bias, float* __restrict__ out) {
    int n = blockIdx.x;
    __shared__ float P[IN_DIM * 4];
    for (int i = threadIdx.x; i < IN_DIM; i += blockDim.x) {
        float xv = x[(size_t)n * IN_DIM + i];
        P[i * 4 + 0] = 1.f;
        P[i * 4 + 1] = xv;
        P[i * 4 + 2] = xv * xv;
        P[i * 4 + 3] = xv * xv * xv;
    }
    __syncthreads();
    for (int o = threadIdx.x; o < OUT_DIM; o += blockDim.x) {
        float s = bias[o];
        const float* c = coeffs + (size_t)o * (IN_DIM * 4);
        for (int i = 0; i < IN_DIM; ++i) {
            float4 cv = *reinterpret_cast<const float4*>(c + i * 4);
            s += cv.x * P[i * 4 + 0] + cv.y * P[i * 4 + 1] +
                 cv.z * P[i * 4 + 2] + cv.w * P[i * 4 + 3];
        }
        out[(size_t)n * OUT_DIM + o] = s;
    }
}

extern "C" void kernel_launch(void* const* d_in, const int* in_sizes, int n_in,
                              void* d_out, int out_size, void* d_ws, size_t ws_size,
                              hipStream_t stream) {
    const float* x = (const float*)d_in[0];
    const float* coeffs = (const float*)d_in[1];
    const float* bias = (const float*)d_in[2];
    float* out = (float*)d_out;

    const size_t needA = (size_t)NROWS * KD * 2;     // 48 MiB
    const size_t needB = (size_t)OUT_DIM * KD * 2;   // 6 MiB
    const size_t needBias = OUT_DIM * sizeof(float); // 4 KiB

    if (ws_size >= needA + needB + needBias) {
        unsigned short* A = (unsigned short*)d_ws;
        unsigned short* B = (unsigned short*)((char*)d_ws + needA);
        float* bias2 = (float*)((char*)d_ws + needA + needB);
        taylor_prep<<<8192 + 1024, 256, 0, stream>>>(x, coeffs, bias, A, B, bias2);
        dim3 grid(NROWS / BM, OUT_DIM / BN);   // (32, 8) = 256 blocks, 1/CU
        taylor_gemm<<<grid, 512, 0, stream>>>(A, B, bias2, out);
    } else {
        taylor_naive<<<NROWS, 256, 0, stream>>>(x, coeffs, bias, out);
    }
}